// Round 3
// baseline (804.032 us; speedup 1.0000x reference)
//
#include <hip/hip_runtime.h>
#include <cstdint>
#include <cstddef>

// Problem constants
#define DN 2048      // nodes
#define DB 16        // batch
#define DE 32768     // edges
#define FPAD 96      // F=66 padded to 96 (3 x K32 MFMA chunks)

typedef __bf16 bf16x8 __attribute__((ext_vector_type(8)));
typedef float f32x4 __attribute__((ext_vector_type(4)));

// ---------------------------------------------------------------------------
// prep: xcat1 = bf16[inputs | hx | 0pad], xcat2 = bf16[inputs | 0 (r*hx later) | 0pad],
//       wtru[o][k] = bf16 W_ru[k*3 + o/128][o%128], wtc[o][k] = bf16 W_c[k*3+o/64][o%64]
// All global float inputs are FP32 (reference dtype); internal compute bf16.
// ---------------------------------------------------------------------------
__global__ __launch_bounds__(256) void prep_kernel(
    const float* __restrict__ inputs, const float* __restrict__ hx,
    const float* __restrict__ Wru, const float* __restrict__ Wc,
    __bf16* __restrict__ xcat1, __bf16* __restrict__ xcat2,
    __bf16* __restrict__ wtru, __bf16* __restrict__ wtc) {
  int idx = blockIdx.x * 256 + threadIdx.x;
  const int T1 = DB * DN * FPAD;  // 3145728
  if (idx < 2 * T1) {
    int which = idx >= T1 ? 1 : 0;
    int i = idx - which * T1;
    int f = i % FPAD;
    int bn = i / FPAD;
    int n = bn & (DN - 1);
    int b = bn >> 11;
    __bf16 v = (__bf16)0.0f;
    if (f < 2) v = (__bf16)inputs[(b << 12) + n * 2 + f];
    else if (f < 66 && !which) v = (__bf16)hx[((size_t)b << 17) + (n << 6) + (f - 2)];
    if (which) xcat2[i] = v; else xcat1[i] = v;
  } else {
    int j = idx - 2 * T1;
    if (j < 384 * FPAD) {
      int k = j % FPAD, o = j / FPAD;
      wtru[j] = (k < 66) ? (__bf16)Wru[(k * 3 + (o >> 7)) * 128 + (o & 127)] : (__bf16)0.0f;
    } else {
      j -= 384 * FPAD;
      if (j < 192 * FPAD) {
        int k = j % FPAD, o = j / FPAD;
        wtc[j] = (k < 66) ? (__bf16)Wc[(k * 3 + (o >> 6)) * 64 + (o & 63)] : (__bf16)0.0f;
      }
    }
  }
}

// ---------------------------------------------------------------------------
// CSR build (single block, 1024 thr): count -> Hillis-Steele scan -> scatter
// ---------------------------------------------------------------------------
__global__ __launch_bounds__(1024) void build_csr(
    const int* __restrict__ rows, const int* __restrict__ cols,
    const float* __restrict__ vals,
    int* __restrict__ csr_ptr, int* __restrict__ csr_col,
    float* __restrict__ csr_val) {
  __shared__ int cnt[DN];
  __shared__ int sa[DN];
  __shared__ int sb[DN];
  int t = threadIdx.x;
  cnt[t] = 0; cnt[t + 1024] = 0;
  __syncthreads();
  for (int e = t; e < DE; e += 1024) atomicAdd(&cnt[rows[e]], 1);
  __syncthreads();
  sa[t] = cnt[t]; sa[t + 1024] = cnt[t + 1024];
  __syncthreads();
  int* src = sa; int* dst = sb;
  for (int off = 1; off < DN; off <<= 1) {
    for (int i = t; i < DN; i += 1024) {
      int v = src[i];
      if (i >= off) v += src[i - off];
      dst[i] = v;
    }
    __syncthreads();
    int* tmp = src; src = dst; dst = tmp;
  }
  // src holds inclusive scan; exclusive = inc - cnt
  int e0 = src[t] - cnt[t];
  int e1 = src[t + 1024] - cnt[t + 1024];
  csr_ptr[t] = e0; csr_ptr[t + 1024] = e1;
  if (t == 0) csr_ptr[DN] = DE;
  dst[t] = e0; dst[t + 1024] = e1;   // dst != src: running offsets
  __syncthreads();
  for (int e = t; e < DE; e += 1024) {
    int r = rows[e];
    int p = atomicAdd(&dst[r], 1);
    csr_col[p] = cols[e];
    csr_val[p] = vals[e];
  }
}

// ---------------------------------------------------------------------------
// small GEMM: Y[row, o'] = sum_k xcat[row,k] * WcatT[o'][k], row in [0,32768)
// Block 128x64, 4 waves (2x2), wave tile 64x32 (MT=4,NT=2), K=96 single stage.
// Col group g = o'/OD: g0 -> Y0 (f32), g1 -> y1b (bf16), g2 -> y2b (bf16)
// ---------------------------------------------------------------------------
template <int OD>
__global__ __launch_bounds__(256) void small_gemm(
    const __bf16* __restrict__ A, const __bf16* __restrict__ Bt,
    float* __restrict__ Y0, __bf16* __restrict__ y1b, __bf16* __restrict__ y2b) {
  __shared__ __attribute__((aligned(16))) __bf16 As[128 * 104];
  __shared__ __attribute__((aligned(16))) __bf16 Bs[64 * 104];
  int tid = threadIdx.x;
  int wave = tid >> 6, lane = tid & 63;
  int lrow = lane & 15, quad = lane >> 4;
  int r0 = blockIdx.x * 128;
  int c0 = blockIdx.y * 64;
  const uint4* gA = (const uint4*)(A + (size_t)r0 * FPAD);
  const uint4* gB = (const uint4*)(Bt + (size_t)c0 * FPAD);
  uint4* sA = (uint4*)As;
  uint4* sB = (uint4*)Bs;
#pragma unroll
  for (int i = 0; i < 6; ++i) {  // 128*12 uint4
    int s = i * 256 + tid;
    int r = s / 12, c4 = s % 12;
    sA[r * 13 + c4] = gA[r * 12 + c4];
  }
#pragma unroll
  for (int i = 0; i < 3; ++i) {  // 64*12 uint4
    int s = i * 256 + tid;
    int r = s / 12, c4 = s % 12;
    sB[r * 13 + c4] = gB[r * 12 + c4];
  }
  __syncthreads();
  int wm = wave >> 1, wn = wave & 1;
  f32x4 acc[4][2];
#pragma unroll
  for (int mt = 0; mt < 4; ++mt)
#pragma unroll
    for (int nt = 0; nt < 2; ++nt) acc[mt][nt] = (f32x4){0.f, 0.f, 0.f, 0.f};
#pragma unroll
  for (int kk = 0; kk < 3; ++kk) {
    bf16x8 af[4], bv[2];
#pragma unroll
    for (int mt = 0; mt < 4; ++mt)
      af[mt] = *(const bf16x8*)(As + (wm * 64 + mt * 16 + lrow) * 104 + kk * 32 + quad * 8);
#pragma unroll
    for (int nt = 0; nt < 2; ++nt)
      bv[nt] = *(const bf16x8*)(Bs + (wn * 32 + nt * 16 + lrow) * 104 + kk * 32 + quad * 8);
#pragma unroll
    for (int mt = 0; mt < 4; ++mt)
#pragma unroll
      for (int nt = 0; nt < 2; ++nt)
        acc[mt][nt] = __builtin_amdgcn_mfma_f32_16x16x32_bf16(af[mt], bv[nt], acc[mt][nt], 0, 0, 0);
  }
#pragma unroll
  for (int mt = 0; mt < 4; ++mt)
#pragma unroll
    for (int nt = 0; nt < 2; ++nt)
#pragma unroll
      for (int r = 0; r < 4; ++r) {
        int row = r0 + wm * 64 + mt * 16 + quad * 4 + r;
        int col = c0 + wn * 32 + nt * 16 + lrow;
        float v = acc[mt][nt][r];
        int g = col >> ((OD == 128) ? 7 : 6);
        int oo = col & (OD - 1);
        size_t oi = (size_t)row * OD + oo;
        if (g == 0) Y0[oi] = v;
        else if (g == 1) y1b[oi] = (__bf16)v;
        else y2b[oi] = (__bf16)v;
      }
}

// ---------------------------------------------------------------------------
// pre = Y0 + S*Y1 (CSR gather), in place over Y0
// ---------------------------------------------------------------------------
template <int OD>
__global__ __launch_bounds__(256) void gather_pre(
    float* __restrict__ Y0, const __bf16* __restrict__ y1b,
    const int* __restrict__ csr_ptr, const int* __restrict__ csr_col,
    const float* __restrict__ csr_val) {
  constexpr int SH = (OD == 128) ? 7 : 6;
  int idx = blockIdx.x * 256 + threadIdx.x;  // B*N*OD total
  int o = idx & (OD - 1);
  int bn = idx >> SH;
  int n = bn & (DN - 1);
  int b = bn >> 11;
  float acc = Y0[idx];
  int e1 = csr_ptr[n + 1];
  const __bf16* yb = y1b + ((size_t)b << 11) * OD;
  for (int e = csr_ptr[n]; e < e1; ++e)
    acc += csr_val[e] * (float)yb[(size_t)csr_col[e] * OD + o];
  Y0[idx] = acc;
}

// ---------------------------------------------------------------------------
// transpose y2b (b, m, o) -> y2t (b, o, m)
// ---------------------------------------------------------------------------
template <int OD>
__global__ void transpose_y2(const __bf16* __restrict__ y2b, __bf16* __restrict__ y2t) {
  __shared__ __bf16 tile[32][33];
  int b = blockIdx.z;
  int mb = blockIdx.x * 32, ob = blockIdx.y * 32;
  int tx = threadIdx.x, ty = threadIdx.y;  // (32,8)
#pragma unroll
  for (int i = 0; i < 4; ++i)
    tile[ty + i * 8][tx] = y2b[(size_t)(b * DN + mb + ty + i * 8) * OD + ob + tx];
  __syncthreads();
#pragma unroll
  for (int i = 0; i < 4; ++i)
    y2t[(size_t)(b * OD + ob + ty + i * 8) * DN + mb + tx] = tile[tx][ty + i * 8];
}

// ---------------------------------------------------------------------------
// adp GEMM + fused epilogue.  G[b,n,o] = sum_m adp[b,n,m]*Y2[b,m,o] + pre
//  IS_RU: s = sigmoid(G); o<64 -> xcat2[...,2+o] = bf16(s*hx) (r-gate),
//         o>=64 -> u_buf = s
//  else : c = tanh(G); out = u*hx + (1-u)*c  -> d_out (f32)
// adp is FP32: stage via 2x float4 -> VGPR, convert to bf16x8, ds_write_b128
// into padded (stride-72) unswizzled LDS. y2t is bf16 (16B loads).
// ---------------------------------------------------------------------------
template <int OD, int WGM, int WGN, int MT, int NT, bool IS_RU>
__global__ __launch_bounds__(256) void adp_gemm(
    const float* __restrict__ adp, const __bf16* __restrict__ y2t,
    const float* __restrict__ pre, const float* __restrict__ hx,
    float* __restrict__ u_buf, __bf16* __restrict__ xcat2,
    float* __restrict__ outp) {
  constexpr int BM = WGM * MT * 16;  // 128
  constexpr int BN = WGN * NT * 16;  // 128 (ru) / 64 (c)
  constexpr int LDK = 72;            // padded LDS row stride (elements), 144 B
  constexpr int NA = (BM * 8) / 256; // 8-elem slots per thread for A tile
  constexpr int NB = (BN * 8) / 256;
  __shared__ __attribute__((aligned(16))) __bf16 As[BM * LDK];
  __shared__ __attribute__((aligned(16))) __bf16 Bs[BN * LDK];
  int tid = threadIdx.x;
  int wave = tid >> 6, lane = tid & 63;
  int lrow = lane & 15, quad = lane >> 4;
  int b = blockIdx.y;
  int row0 = blockIdx.x * BM;
  const float* Ab = adp + ((size_t)b * DN + row0) * DN;
  const __bf16* Bb = y2t + (size_t)b * OD * DN;
  int wm = wave / WGN, wn = wave % WGN;
  f32x4 acc[MT][NT];
#pragma unroll
  for (int mt = 0; mt < MT; ++mt)
#pragma unroll
    for (int nt = 0; nt < NT; ++nt) acc[mt][nt] = (f32x4){0.f, 0.f, 0.f, 0.f};

  for (int c = 0; c < DN / 64; ++c) {
    int k0 = c * 64;
    f32x4 ra[NA][2];
    uint4 rb[NB];
#pragma unroll
    for (int i = 0; i < NA; ++i) {
      int s = i * 256 + tid, r = s >> 3, cc = s & 7;
      const float* p = Ab + (size_t)r * DN + k0 + cc * 8;
      ra[i][0] = *(const f32x4*)p;
      ra[i][1] = *(const f32x4*)(p + 4);
    }
#pragma unroll
    for (int i = 0; i < NB; ++i) {
      int s = i * 256 + tid, r = s >> 3, cc = s & 7;
      rb[i] = *(const uint4*)(Bb + (size_t)r * DN + k0 + cc * 8);
    }
    __syncthreads();  // all waves done reading previous LDS tile
#pragma unroll
    for (int i = 0; i < NA; ++i) {
      int s = i * 256 + tid, r = s >> 3, cc = s & 7;
      bf16x8 cv;
#pragma unroll
      for (int j = 0; j < 4; ++j) cv[j] = (__bf16)ra[i][0][j];
#pragma unroll
      for (int j = 0; j < 4; ++j) cv[4 + j] = (__bf16)ra[i][1][j];
      *(bf16x8*)(As + r * LDK + cc * 8) = cv;
    }
#pragma unroll
    for (int i = 0; i < NB; ++i) {
      int s = i * 256 + tid, r = s >> 3, cc = s & 7;
      *(uint4*)(Bs + r * LDK + cc * 8) = rb[i];
    }
    __syncthreads();
#pragma unroll
    for (int kk = 0; kk < 2; ++kk) {
      bf16x8 af[MT], bv[NT];
#pragma unroll
      for (int mt = 0; mt < MT; ++mt) {
        int r = wm * MT * 16 + mt * 16 + lrow;
        af[mt] = *(const bf16x8*)(As + r * LDK + (kk * 4 + quad) * 8);
      }
#pragma unroll
      for (int nt = 0; nt < NT; ++nt) {
        int r = wn * NT * 16 + nt * 16 + lrow;
        bv[nt] = *(const bf16x8*)(Bs + r * LDK + (kk * 4 + quad) * 8);
      }
#pragma unroll
      for (int mt = 0; mt < MT; ++mt)
#pragma unroll
        for (int nt = 0; nt < NT; ++nt)
          acc[mt][nt] = __builtin_amdgcn_mfma_f32_16x16x32_bf16(af[mt], bv[nt], acc[mt][nt], 0, 0, 0);
    }
  }
  // epilogue
#pragma unroll
  for (int mt = 0; mt < MT; ++mt)
#pragma unroll
    for (int nt = 0; nt < NT; ++nt)
#pragma unroll
      for (int r = 0; r < 4; ++r) {
        int n = row0 + wm * MT * 16 + mt * 16 + quad * 4 + r;
        int o = wn * NT * 16 + nt * 16 + lrow;
        float g = acc[mt][nt][r] + pre[((size_t)b * DN + n) * OD + o];
        if (IS_RU) {
          float s = 1.f / (1.f + __expf(-g));
          if (o < 64) {  // r gate (wave-uniform: o<64 <=> wn==0)
            float hxv = hx[((size_t)b << 17) + n * 64 + o];
            xcat2[((size_t)b * DN + n) * FPAD + 2 + o] = (__bf16)(s * hxv);
          } else {       // u gate
            u_buf[((size_t)b * DN + n) * 64 + (o - 64)] = s;
          }
        } else {
          float cval = 1.f - 2.f / (__expf(2.f * g) + 1.f);  // tanh
          float u = u_buf[((size_t)b * DN + n) * 64 + o];
          float hxv = hx[((size_t)b << 17) + n * 64 + o];
          outp[((size_t)b << 17) + n * 64 + o] = u * hxv + (1.f - u) * cval;
        }
      }
}

// ---------------------------------------------------------------------------
extern "C" void kernel_launch(void* const* d_in, const int* in_sizes, int n_in,
                              void* d_out, int out_size, void* d_ws, size_t ws_size,
                              hipStream_t stream) {
  const float* inputs = (const float*)d_in[0];
  const float* hx     = (const float*)d_in[1];
  const float* adp    = (const float*)d_in[2];
  const int* srows    = (const int*)d_in[3];
  const int* scols    = (const int*)d_in[4];
  const float* svals  = (const float*)d_in[5];
  const float* Wru    = (const float*)d_in[6];
  const float* Wc     = (const float*)d_in[7];
  float* outp = (float*)d_out;

  char* w = (char*)d_ws;
  auto carve = [&](size_t bytes) -> char* {
    char* p = w;
    w += (bytes + 255) & ~(size_t)255;
    return p;
  };
  int*    csr_ptr = (int*)   carve((DN + 1) * sizeof(int));
  int*    csr_col = (int*)   carve(DE * sizeof(int));
  float*  csr_val = (float*) carve(DE * sizeof(float));
  __bf16* xcat1   = (__bf16*)carve((size_t)DB * DN * FPAD * 2);
  __bf16* xcat2   = (__bf16*)carve((size_t)DB * DN * FPAD * 2);
  __bf16* wtru    = (__bf16*)carve(384 * FPAD * 2);
  __bf16* wtc     = (__bf16*)carve(192 * FPAD * 2);
  float*  Y0      = (float*) carve((size_t)DB * DN * 128 * 4);  // doubles as `pre`
  __bf16* y1b     = (__bf16*)carve((size_t)DB * DN * 128 * 2);
  __bf16* y2b     = (__bf16*)carve((size_t)DB * DN * 128 * 2);
  __bf16* y2t     = (__bf16*)carve((size_t)DB * DN * 128 * 2);
  float*  u_buf   = (float*) carve((size_t)DB * DN * 64 * 4);
  (void)ws_size; (void)in_sizes; (void)n_in; (void)out_size;

  prep_kernel<<<24792, 256, 0, stream>>>(inputs, hx, Wru, Wc, xcat1, xcat2, wtru, wtc);
  build_csr<<<1, 1024, 0, stream>>>(srows, scols, svals, csr_ptr, csr_col, csr_val);

  // ---- gconv 1 (r,u gates; OD = 128) ----
  small_gemm<128><<<dim3(256, 6), 256, 0, stream>>>(xcat1, wtru, Y0, y1b, y2b);
  gather_pre<128><<<16384, 256, 0, stream>>>(Y0, y1b, csr_ptr, csr_col, csr_val);
  transpose_y2<128><<<dim3(64, 4, 16), dim3(32, 8), 0, stream>>>(y2b, y2t);
  adp_gemm<128, 2, 2, 4, 4, true><<<dim3(16, 16), 256, 0, stream>>>(
      adp, y2t, Y0, hx, u_buf, xcat2, outp);

  // ---- gconv 2 (candidate c; OD = 64) ----
  small_gemm<64><<<dim3(256, 3), 256, 0, stream>>>(xcat2, wtc, Y0, y1b, y2b);
  gather_pre<64><<<8192, 256, 0, stream>>>(Y0, y1b, csr_ptr, csr_col, csr_val);
  transpose_y2<64><<<dim3(64, 2, 16), dim3(32, 8), 0, stream>>>(y2b, y2t);
  adp_gemm<64, 4, 1, 2, 4, false><<<dim3(16, 16), 256, 0, stream>>>(
      adp, y2t, Y0, hx, u_buf, xcat2, outp);
}

// Round 4
// 721.841 us; speedup vs baseline: 1.1139x; 1.1139x over previous
//
#include <hip/hip_runtime.h>
#include <cstdint>
#include <cstddef>

// Problem constants
#define DN 2048      // nodes
#define DB 16        // batch
#define DE 32768     // edges
#define FPAD 96      // F=66 padded to 96 (3 x K32 MFMA chunks)

typedef __bf16 bf16x8 __attribute__((ext_vector_type(8)));
typedef float f32x4 __attribute__((ext_vector_type(4)));

// ---------------------------------------------------------------------------
// prep: xcat1 = bf16[inputs | hx | 0pad], xcat2 = bf16[inputs | 0 (r*hx later) | 0pad],
//       wtru[o][k] = bf16 W_ru[k*3 + o/128][o%128], wtc[o][k] = bf16 W_c[k*3+o/64][o%64]
//       + zero cnt[2048] for the CSR count pass.
// ---------------------------------------------------------------------------
__global__ __launch_bounds__(256) void prep_kernel(
    const float* __restrict__ inputs, const float* __restrict__ hx,
    const float* __restrict__ Wru, const float* __restrict__ Wc,
    __bf16* __restrict__ xcat1, __bf16* __restrict__ xcat2,
    __bf16* __restrict__ wtru, __bf16* __restrict__ wtc,
    int* __restrict__ cnt) {
  int idx = blockIdx.x * 256 + threadIdx.x;
  const int T1 = DB * DN * FPAD;  // 3145728
  if (idx < 2 * T1) {
    int which = idx >= T1 ? 1 : 0;
    int i = idx - which * T1;
    int f = i % FPAD;
    int bn = i / FPAD;
    int n = bn & (DN - 1);
    int b = bn >> 11;
    __bf16 v = (__bf16)0.0f;
    if (f < 2) v = (__bf16)inputs[(b << 12) + n * 2 + f];
    else if (f < 66 && !which) v = (__bf16)hx[((size_t)b << 17) + (n << 6) + (f - 2)];
    if (which) xcat2[i] = v; else xcat1[i] = v;
  } else {
    int j = idx - 2 * T1;
    if (j < 384 * FPAD) {
      int k = j % FPAD, o = j / FPAD;
      wtru[j] = (k < 66) ? (__bf16)Wru[(k * 3 + (o >> 7)) * 128 + (o & 127)] : (__bf16)0.0f;
    } else {
      j -= 384 * FPAD;
      if (j < 192 * FPAD) {
        int k = j % FPAD, o = j / FPAD;
        wtc[j] = (k < 66) ? (__bf16)Wc[(k * 3 + (o >> 6)) * 64 + (o & 63)] : (__bf16)0.0f;
      } else {
        j -= 192 * FPAD;
        if (j < DN) cnt[j] = 0;
      }
    }
  }
}

// ---------------------------------------------------------------------------
// CSR build, parallel: count (one edge/thread) -> scan (1 block) -> scatter
// ---------------------------------------------------------------------------
__global__ __launch_bounds__(512) void csr_count(const int* __restrict__ rows,
                                                 int* __restrict__ cnt) {
  int e = blockIdx.x * 512 + threadIdx.x;
  atomicAdd(&cnt[rows[e]], 1);
}

__global__ __launch_bounds__(1024) void csr_scan(const int* __restrict__ cnt,
                                                 int* __restrict__ csr_ptr,
                                                 int* __restrict__ off) {
  __shared__ int sa[DN];
  __shared__ int sb[DN];
  int t = threadIdx.x;
  int c0 = cnt[t], c1 = cnt[t + 1024];
  sa[t] = c0; sa[t + 1024] = c1;
  __syncthreads();
  int* src = sa; int* dst = sb;
  for (int o = 1; o < DN; o <<= 1) {
    for (int i = t; i < DN; i += 1024) {
      int v = src[i];
      if (i >= o) v += src[i - o];
      dst[i] = v;
    }
    __syncthreads();
    int* tmp = src; src = dst; dst = tmp;
  }
  int e0 = src[t] - c0;          // exclusive
  int e1 = src[t + 1024] - c1;
  csr_ptr[t] = e0; csr_ptr[t + 1024] = e1;
  off[t] = e0; off[t + 1024] = e1;
  if (t == 0) csr_ptr[DN] = DE;
}

__global__ __launch_bounds__(512) void csr_scatter(
    const int* __restrict__ rows, const int* __restrict__ cols,
    const float* __restrict__ vals, int* __restrict__ off,
    int* __restrict__ csr_col, float* __restrict__ csr_val) {
  int e = blockIdx.x * 512 + threadIdx.x;
  int r = rows[e];
  int p = atomicAdd(&off[r], 1);
  csr_col[p] = cols[e];
  csr_val[p] = vals[e];
}

// ---------------------------------------------------------------------------
// small GEMM: Y[row, o'] = sum_k xcat[row,k] * WcatT[o'][k], row in [0,32768)
// Block 128x64, 4 waves (2x2), wave tile 64x32 (MT=4,NT=2), K=96 single stage.
// Col group g = o'/OD: g0 -> Y0 (f32), g1 -> y1b (bf16), g2 -> y2b (bf16)
// ---------------------------------------------------------------------------
template <int OD>
__global__ __launch_bounds__(256) void small_gemm(
    const __bf16* __restrict__ A, const __bf16* __restrict__ Bt,
    float* __restrict__ Y0, __bf16* __restrict__ y1b, __bf16* __restrict__ y2b) {
  __shared__ __attribute__((aligned(16))) __bf16 As[128 * 104];
  __shared__ __attribute__((aligned(16))) __bf16 Bs[64 * 104];
  int tid = threadIdx.x;
  int wave = tid >> 6, lane = tid & 63;
  int lrow = lane & 15, quad = lane >> 4;
  int r0 = blockIdx.x * 128;
  int c0 = blockIdx.y * 64;
  const uint4* gA = (const uint4*)(A + (size_t)r0 * FPAD);
  const uint4* gB = (const uint4*)(Bt + (size_t)c0 * FPAD);
  uint4* sA = (uint4*)As;
  uint4* sB = (uint4*)Bs;
#pragma unroll
  for (int i = 0; i < 6; ++i) {  // 128*12 uint4
    int s = i * 256 + tid;
    int r = s / 12, c4 = s % 12;
    sA[r * 13 + c4] = gA[r * 12 + c4];
  }
#pragma unroll
  for (int i = 0; i < 3; ++i) {  // 64*12 uint4
    int s = i * 256 + tid;
    int r = s / 12, c4 = s % 12;
    sB[r * 13 + c4] = gB[r * 12 + c4];
  }
  __syncthreads();
  int wm = wave >> 1, wn = wave & 1;
  f32x4 acc[4][2];
#pragma unroll
  for (int mt = 0; mt < 4; ++mt)
#pragma unroll
    for (int nt = 0; nt < 2; ++nt) acc[mt][nt] = (f32x4){0.f, 0.f, 0.f, 0.f};
#pragma unroll
  for (int kk = 0; kk < 3; ++kk) {
    bf16x8 af[4], bv[2];
#pragma unroll
    for (int mt = 0; mt < 4; ++mt)
      af[mt] = *(const bf16x8*)(As + (wm * 64 + mt * 16 + lrow) * 104 + kk * 32 + quad * 8);
#pragma unroll
    for (int nt = 0; nt < 2; ++nt)
      bv[nt] = *(const bf16x8*)(Bs + (wn * 32 + nt * 16 + lrow) * 104 + kk * 32 + quad * 8);
#pragma unroll
    for (int mt = 0; mt < 4; ++mt)
#pragma unroll
      for (int nt = 0; nt < 2; ++nt)
        acc[mt][nt] = __builtin_amdgcn_mfma_f32_16x16x32_bf16(af[mt], bv[nt], acc[mt][nt], 0, 0, 0);
  }
#pragma unroll
  for (int mt = 0; mt < 4; ++mt)
#pragma unroll
    for (int nt = 0; nt < 2; ++nt)
#pragma unroll
      for (int r = 0; r < 4; ++r) {
        int row = r0 + wm * 64 + mt * 16 + quad * 4 + r;
        int col = c0 + wn * 32 + nt * 16 + lrow;
        float v = acc[mt][nt][r];
        int g = col >> ((OD == 128) ? 7 : 6);
        int oo = col & (OD - 1);
        size_t oi = (size_t)row * OD + oo;
        if (g == 0) Y0[oi] = v;
        else if (g == 1) y1b[oi] = (__bf16)v;
        else y2b[oi] = (__bf16)v;
      }
}

// ---------------------------------------------------------------------------
// pre = Y0 + S*Y1 (CSR gather), in place over Y0
// ---------------------------------------------------------------------------
template <int OD>
__global__ __launch_bounds__(256) void gather_pre(
    float* __restrict__ Y0, const __bf16* __restrict__ y1b,
    const int* __restrict__ csr_ptr, const int* __restrict__ csr_col,
    const float* __restrict__ csr_val) {
  constexpr int SH = (OD == 128) ? 7 : 6;
  int idx = blockIdx.x * 256 + threadIdx.x;  // B*N*OD total
  int o = idx & (OD - 1);
  int bn = idx >> SH;
  int n = bn & (DN - 1);
  int b = bn >> 11;
  float acc = Y0[idx];
  int e1 = csr_ptr[n + 1];
  const __bf16* yb = y1b + ((size_t)b << 11) * OD;
  for (int e = csr_ptr[n]; e < e1; ++e)
    acc += csr_val[e] * (float)yb[(size_t)csr_col[e] * OD + o];
  Y0[idx] = acc;
}

// ---------------------------------------------------------------------------
// transpose y2b (b, m, o) -> y2t (b, o, m)
// ---------------------------------------------------------------------------
template <int OD>
__global__ void transpose_y2(const __bf16* __restrict__ y2b, __bf16* __restrict__ y2t) {
  __shared__ __bf16 tile[32][33];
  int b = blockIdx.z;
  int mb = blockIdx.x * 32, ob = blockIdx.y * 32;
  int tx = threadIdx.x, ty = threadIdx.y;  // (32,8)
#pragma unroll
  for (int i = 0; i < 4; ++i)
    tile[ty + i * 8][tx] = y2b[(size_t)(b * DN + mb + ty + i * 8) * OD + ob + tx];
  __syncthreads();
#pragma unroll
  for (int i = 0; i < 4; ++i)
    y2t[(size_t)(b * OD + ob + ty + i * 8) * DN + mb + tx] = tile[tx][ty + i * 8];
}

// ---------------------------------------------------------------------------
// adp GEMM + fused epilogue.  G[b,n,o] = sum_m adp[b,n,m]*Y2[b,m,o] + pre
//  IS_RU: s = sigmoid(G); o<64 -> xcat2[...,2+o] = bf16(s*hx); o>=64 -> u_buf = s
//  else : c = tanh(G); out = u*hx + (1-u)*c  -> d_out (f32)
// Round-4 structure: BM=64 (grid 32x16 = 512 blocks = 2 blocks/CU) and a
// software-pipelined K-loop: barrier -> ds_write(vmcnt drain) -> barrier ->
// issue prefetch(c+1) -> MFMA compute(c).  Prefetch latency hides under the
// MFMA block + the co-resident block.
// Waves 2x2; wave tile 32 x (OD/2): MT=2, NT=OD/32.
// ---------------------------------------------------------------------------
template <int OD, bool IS_RU>
__global__ __launch_bounds__(256) void adp_gemm(
    const float* __restrict__ adp, const __bf16* __restrict__ y2t,
    const float* __restrict__ pre, const float* __restrict__ hx,
    float* __restrict__ u_buf, __bf16* __restrict__ xcat2,
    float* __restrict__ outp) {
  constexpr int BM = 64;
  constexpr int BN = OD;             // 128 (ru) / 64 (c)
  constexpr int MT = 2;
  constexpr int NT = OD / 32;        // 4 / 2
  constexpr int LDK = 72;            // padded LDS row stride (elements), 144 B
  constexpr int NA = (BM * 8) / 256; // 2 slots/thread (8 bf16 each)
  constexpr int NB = (BN * 8) / 256; // 4 / 2
  __shared__ __attribute__((aligned(16))) __bf16 As[BM * LDK];
  __shared__ __attribute__((aligned(16))) __bf16 Bs[BN * LDK];
  int tid = threadIdx.x;
  int wave = tid >> 6, lane = tid & 63;
  int lrow = lane & 15, quad = lane >> 4;
  int b = blockIdx.y;
  int row0 = blockIdx.x * BM;
  const float* Ab = adp + ((size_t)b * DN + row0) * DN;
  const __bf16* Bb = y2t + (size_t)b * OD * DN;
  int wm = wave >> 1, wn = wave & 1;
  f32x4 acc[MT][NT];
#pragma unroll
  for (int mt = 0; mt < MT; ++mt)
#pragma unroll
    for (int nt = 0; nt < NT; ++nt) acc[mt][nt] = (f32x4){0.f, 0.f, 0.f, 0.f};

  f32x4 ra[NA][2];
  uint4 rb[NB];
  // prefetch tile 0
#pragma unroll
  for (int i = 0; i < NA; ++i) {
    int s = i * 256 + tid, r = s >> 3, cc = s & 7;
    const float* p = Ab + (size_t)r * DN + cc * 8;
    ra[i][0] = *(const f32x4*)p;
    ra[i][1] = *(const f32x4*)(p + 4);
  }
#pragma unroll
  for (int i = 0; i < NB; ++i) {
    int s = i * 256 + tid, r = s >> 3, cc = s & 7;
    rb[i] = *(const uint4*)(Bb + (size_t)r * DN + cc * 8);
  }

  for (int c = 0; c < DN / 64; ++c) {
    __syncthreads();  // all waves done reading previous LDS tile
#pragma unroll
    for (int i = 0; i < NA; ++i) {
      int s = i * 256 + tid, r = s >> 3, cc = s & 7;
      bf16x8 cv;
#pragma unroll
      for (int j = 0; j < 4; ++j) cv[j] = (__bf16)ra[i][0][j];
#pragma unroll
      for (int j = 0; j < 4; ++j) cv[4 + j] = (__bf16)ra[i][1][j];
      *(bf16x8*)(As + r * LDK + cc * 8) = cv;
    }
#pragma unroll
    for (int i = 0; i < NB; ++i) {
      int s = i * 256 + tid, r = s >> 3, cc = s & 7;
      *(uint4*)(Bs + r * LDK + cc * 8) = rb[i];
    }
    __syncthreads();
    // issue prefetch for next tile; stays in flight across the MFMA block
    if (c < DN / 64 - 1) {
      int k0 = (c + 1) * 64;
#pragma unroll
      for (int i = 0; i < NA; ++i) {
        int s = i * 256 + tid, r = s >> 3, cc = s & 7;
        const float* p = Ab + (size_t)r * DN + k0 + cc * 8;
        ra[i][0] = *(const f32x4*)p;
        ra[i][1] = *(const f32x4*)(p + 4);
      }
#pragma unroll
      for (int i = 0; i < NB; ++i) {
        int s = i * 256 + tid, r = s >> 3, cc = s & 7;
        rb[i] = *(const uint4*)(Bb + (size_t)r * DN + k0 + cc * 8);
      }
    }
#pragma unroll
    for (int kk = 0; kk < 2; ++kk) {
      bf16x8 af[MT], bv[NT];
#pragma unroll
      for (int mt = 0; mt < MT; ++mt) {
        int r = wm * 32 + mt * 16 + lrow;
        af[mt] = *(const bf16x8*)(As + r * LDK + (kk * 4 + quad) * 8);
      }
#pragma unroll
      for (int nt = 0; nt < NT; ++nt) {
        int r = wn * (NT * 16) + nt * 16 + lrow;
        bv[nt] = *(const bf16x8*)(Bs + r * LDK + (kk * 4 + quad) * 8);
      }
#pragma unroll
      for (int mt = 0; mt < MT; ++mt)
#pragma unroll
        for (int nt = 0; nt < NT; ++nt)
          acc[mt][nt] = __builtin_amdgcn_mfma_f32_16x16x32_bf16(af[mt], bv[nt], acc[mt][nt], 0, 0, 0);
    }
  }
  // epilogue
#pragma unroll
  for (int mt = 0; mt < MT; ++mt)
#pragma unroll
    for (int nt = 0; nt < NT; ++nt)
#pragma unroll
      for (int r = 0; r < 4; ++r) {
        int n = row0 + wm * 32 + mt * 16 + quad * 4 + r;
        int o = wn * (NT * 16) + nt * 16 + lrow;
        float g = acc[mt][nt][r] + pre[((size_t)b * DN + n) * OD + o];
        if (IS_RU) {
          float s = 1.f / (1.f + __expf(-g));
          if (o < 64) {  // r gate (wave-uniform: o<64 <=> wn==0)
            float hxv = hx[((size_t)b << 17) + n * 64 + o];
            xcat2[((size_t)b * DN + n) * FPAD + 2 + o] = (__bf16)(s * hxv);
          } else {       // u gate
            u_buf[((size_t)b * DN + n) * 64 + (o - 64)] = s;
          }
        } else {
          float cval = 1.f - 2.f / (__expf(2.f * g) + 1.f);  // tanh
          float u = u_buf[((size_t)b * DN + n) * 64 + o];
          float hxv = hx[((size_t)b << 17) + n * 64 + o];
          outp[((size_t)b << 17) + n * 64 + o] = u * hxv + (1.f - u) * cval;
        }
      }
}

// ---------------------------------------------------------------------------
extern "C" void kernel_launch(void* const* d_in, const int* in_sizes, int n_in,
                              void* d_out, int out_size, void* d_ws, size_t ws_size,
                              hipStream_t stream) {
  const float* inputs = (const float*)d_in[0];
  const float* hx     = (const float*)d_in[1];
  const float* adp    = (const float*)d_in[2];
  const int* srows    = (const int*)d_in[3];
  const int* scols    = (const int*)d_in[4];
  const float* svals  = (const float*)d_in[5];
  const float* Wru    = (const float*)d_in[6];
  const float* Wc     = (const float*)d_in[7];
  float* outp = (float*)d_out;

  char* w = (char*)d_ws;
  auto carve = [&](size_t bytes) -> char* {
    char* p = w;
    w += (bytes + 255) & ~(size_t)255;
    return p;
  };
  int*    csr_ptr = (int*)   carve((DN + 1) * sizeof(int));
  int*    csr_col = (int*)   carve(DE * sizeof(int));
  float*  csr_val = (float*) carve(DE * sizeof(float));
  int*    cnt     = (int*)   carve(DN * sizeof(int));
  int*    off     = (int*)   carve(DN * sizeof(int));
  __bf16* xcat1   = (__bf16*)carve((size_t)DB * DN * FPAD * 2);
  __bf16* xcat2   = (__bf16*)carve((size_t)DB * DN * FPAD * 2);
  __bf16* wtru    = (__bf16*)carve(384 * FPAD * 2);
  __bf16* wtc     = (__bf16*)carve(192 * FPAD * 2);
  float*  Y0      = (float*) carve((size_t)DB * DN * 128 * 4);  // doubles as `pre`
  __bf16* y1b     = (__bf16*)carve((size_t)DB * DN * 128 * 2);
  __bf16* y2b     = (__bf16*)carve((size_t)DB * DN * 128 * 2);
  __bf16* y2t     = (__bf16*)carve((size_t)DB * DN * 128 * 2);
  float*  u_buf   = (float*) carve((size_t)DB * DN * 64 * 4);
  (void)ws_size; (void)in_sizes; (void)n_in; (void)out_size;

  // 2*T1 (6291456) + 36864 + 18432 + 2048 = 6348800 = 24800 * 256
  prep_kernel<<<24800, 256, 0, stream>>>(inputs, hx, Wru, Wc, xcat1, xcat2,
                                         wtru, wtc, cnt);
  csr_count<<<64, 512, 0, stream>>>(srows, cnt);
  csr_scan<<<1, 1024, 0, stream>>>(cnt, csr_ptr, off);
  csr_scatter<<<64, 512, 0, stream>>>(srows, scols, svals, off, csr_col, csr_val);

  // ---- gconv 1 (r,u gates; OD = 128) ----
  small_gemm<128><<<dim3(256, 6), 256, 0, stream>>>(xcat1, wtru, Y0, y1b, y2b);
  gather_pre<128><<<16384, 256, 0, stream>>>(Y0, y1b, csr_ptr, csr_col, csr_val);
  transpose_y2<128><<<dim3(64, 4, 16), dim3(32, 8), 0, stream>>>(y2b, y2t);
  adp_gemm<128, true><<<dim3(32, 16), 256, 0, stream>>>(
      adp, y2t, Y0, hx, u_buf, xcat2, outp);

  // ---- gconv 2 (candidate c; OD = 64) ----
  small_gemm<64><<<dim3(256, 3), 256, 0, stream>>>(xcat2, wtc, Y0, y1b, y2b);
  gather_pre<64><<<8192, 256, 0, stream>>>(Y0, y1b, csr_ptr, csr_col, csr_val);
  transpose_y2<64><<<dim3(64, 2, 16), dim3(32, 8), 0, stream>>>(y2b, y2t);
  adp_gemm<64, false><<<dim3(32, 16), 256, 0, stream>>>(
      adp, y2t, Y0, hx, u_buf, xcat2, outp);
}